// Round 1
// baseline (72.744 us; speedup 1.0000x reference)
//
#include <hip/hip_runtime.h>
#include <hip/hip_bf16.h>

// Problem constants (reference: B,E,P,L,D = 16,2048,16384,5,64)
#define B 16
#define E 2048
#define P 16384
#define L 5
#define D 64
#define EPS 1e-9f

// Kernel 1: proj[b,e,l] = dot(emb[b,e,:], ev[l,:])
// One thread per (b,e) row. 512 blocks x 64 threads = 32768 threads = B*E.
__global__ void edge_proj_kernel(const float* __restrict__ emb,
                                 const float* __restrict__ ev,
                                 float* __restrict__ proj) {
    __shared__ float sev[L * D];  // 320 floats = 1.25 KB
    for (int i = threadIdx.x; i < L * D; i += blockDim.x) sev[i] = ev[i];
    __syncthreads();

    int idx = blockIdx.x * blockDim.x + threadIdx.x;  // (b,e) flat, 0..B*E
    if (idx >= B * E) return;

    const float4* row = (const float4*)(emb + (size_t)idx * D);
    const float4* w4  = (const float4*)sev;

    float acc[L];
#pragma unroll
    for (int l = 0; l < L; ++l) acc[l] = 0.f;

#pragma unroll
    for (int c = 0; c < D / 4; ++c) {
        float4 v = row[c];
#pragma unroll
        for (int l = 0; l < L; ++l) {
            float4 w = w4[l * (D / 4) + c];  // same addr across lanes -> LDS broadcast
            acc[l] += v.x * w.x + v.y * w.y + v.z * w.z + v.w * w.w;
        }
    }

    float* p = proj + (size_t)idx * L;
#pragma unroll
    for (int l = 0; l < L; ++l) p[l] = acc[l];
}

// Kernel 2: out[b,p] = sum_l (path>=0 ? proj[b,path,l] : 0) / (count + EPS)
// One thread per (b,p). Gather is 4B/element from a 40KB-per-batch table (L1/L2 resident).
__global__ void edge_gather_kernel(const int* __restrict__ paths,
                                   const float* __restrict__ proj,
                                   float* __restrict__ out) {
    int idx = blockIdx.x * blockDim.x + threadIdx.x;  // (b,p) flat, 0..B*P
    if (idx >= B * P) return;

    int b = idx >> 14;  // P = 16384 = 2^14
    const float* pb = proj + (size_t)b * E * L;
    const int* pp = paths + (size_t)idx * L;

    float sum = 0.f;
    int cnt = 0;
#pragma unroll
    for (int l = 0; l < L; ++l) {
        int e = pp[l];
        bool valid = (e >= 0);
        // clamp for safe address even when invalid; predicated add
        int ec = valid ? e : 0;
        float v = pb[ec * L + l];
        sum += valid ? v : 0.f;
        cnt += valid ? 1 : 0;
    }
    out[idx] = sum / ((float)cnt + EPS);
}

extern "C" void kernel_launch(void* const* d_in, const int* in_sizes, int n_in,
                              void* d_out, int out_size, void* d_ws, size_t ws_size,
                              hipStream_t stream) {
    const float* emb   = (const float*)d_in[0];  // (B,E,D) f32
    const int*   paths = (const int*)d_in[1];    // (B,P,L) int (harness converts to int32)
    const float* ev    = (const float*)d_in[2];  // (L,D) f32
    float* out  = (float*)d_out;                 // (B,P) f32
    float* proj = (float*)d_ws;                  // (B,E,L) f32 = 640 KB scratch

    edge_proj_kernel<<<(B * E + 63) / 64, 64, 0, stream>>>(emb, ev, proj);
    edge_gather_kernel<<<(B * P + 255) / 256, 256, 0, stream>>>(paths, proj, out);
}

// Round 2
// 68.468 us; speedup vs baseline: 1.0624x; 1.0624x over previous
//
#include <hip/hip_runtime.h>
#include <hip/hip_bf16.h>

// Problem constants (reference: B,E,P,L,D = 16,2048,16384,5,64)
#define B 16
#define E 2048
#define P 16384
#define L 5
#define D 64
#define EPS 1e-9f

// Kernel 1: proj[(b*E+e)*L + l] = dot(emb[b,e,:], ev[l,:])
// Half-row per thread (2 lanes per row, shuffle-combine) -> 65536 threads,
// 1024 waves (4/CU), 8 independent float4 loads in flight per thread.
__global__ __launch_bounds__(256) void edge_proj_kernel(
    const float* __restrict__ emb, const float* __restrict__ ev,
    float* __restrict__ proj) {
    __shared__ float sev[L * D];  // 1.25 KB
    for (int i = threadIdx.x; i < L * D; i += 256) sev[i] = ev[i];
    __syncthreads();

    int gid  = blockIdx.x * 256 + threadIdx.x;  // 0 .. 2*B*E-1
    int row  = gid >> 1;                        // (b,e) flat
    int half = gid & 1;                         // which 32-float half of D

    const float4* src = (const float4*)(emb + (size_t)row * D + half * 32);
    const float4* w4  = (const float4*)sev;

    float acc[L] = {0.f, 0.f, 0.f, 0.f, 0.f};
#pragma unroll
    for (int c = 0; c < 8; ++c) {
        float4 v = src[c];
#pragma unroll
        for (int l = 0; l < L; ++l) {
            float4 w = w4[l * 16 + half * 8 + c];  // LDS broadcast across lanes
            acc[l] += v.x * w.x + v.y * w.y + v.z * w.z + v.w * w.w;
        }
    }
    // combine the two halves (lanes 2r, 2r+1 are in the same wave)
#pragma unroll
    for (int l = 0; l < L; ++l) acc[l] += __shfl_xor(acc[l], 1);

    if (half == 0) {
        float* p = proj + (size_t)row * L;
#pragma unroll
        for (int l = 0; l < L; ++l) p[l] = acc[l];
    }
}

// Kernel 2: stage proj[b] (40 KB) into LDS with coalesced float4 loads, then
// gather from LDS. out[b,p] = sum_l valid*proj / (count + EPS).
// 16 blocks per batch (g = path chunk), 256 blocks total, 4 paths/thread.
__global__ __launch_bounds__(256) void edge_gather_kernel(
    const int* __restrict__ paths, const float* __restrict__ proj,
    float* __restrict__ out) {
    __shared__ float sproj[E * L];  // 40 KB
    int b = blockIdx.x & 15;
    int g = blockIdx.x >> 4;

    const float4* src = (const float4*)(proj + (size_t)b * E * L);
    float4* dst = (float4*)sproj;
#pragma unroll
    for (int i = 0; i < (E * L) / 4 / 256; ++i)  // 10 float4 per thread
        dst[threadIdx.x + i * 256] = src[threadIdx.x + i * 256];
    __syncthreads();

    int pbase = g * (P / 16);  // 1024 paths per block
#pragma unroll
    for (int k = 0; k < 4; ++k) {
        int p = pbase + k * 256 + threadIdx.x;
        const int* pp = paths + ((size_t)b * P + p) * L;
        float sum = 0.f;
        int cnt = 0;
#pragma unroll
        for (int l = 0; l < L; ++l) {
            int e = pp[l];
            bool valid = (e >= 0);
            int ec = valid ? e : 0;
            float v = sproj[ec * L + l];
            sum += valid ? v : 0.f;
            cnt += valid ? 1 : 0;
        }
        out[(size_t)b * P + p] = sum / ((float)cnt + EPS);
    }
}

extern "C" void kernel_launch(void* const* d_in, const int* in_sizes, int n_in,
                              void* d_out, int out_size, void* d_ws, size_t ws_size,
                              hipStream_t stream) {
    const float* emb   = (const float*)d_in[0];  // (B,E,D) f32
    const int*   paths = (const int*)d_in[1];    // (B,P,L) int32
    const float* ev    = (const float*)d_in[2];  // (L,D) f32
    float* out  = (float*)d_out;                 // (B,P) f32
    float* proj = (float*)d_ws;                  // (B,E,L) f32 = 640 KB scratch

    edge_proj_kernel<<<(2 * B * E) / 256, 256, 0, stream>>>(emb, ev, proj);
    edge_gather_kernel<<<16 * B, 256, 0, stream>>>(paths, proj, out);
}